// Round 1
// baseline (311.912 us; speedup 1.0000x reference)
//
#include <hip/hip_runtime.h>
#include <math.h>

#define BATCH 4
#define TU 4096
#define TM 2048
#define DM 1024
#define FF 2048          // 2*D
#define KB 4             // max births
#define NROWS (BATCH*KB) // 16
#define OUT_TM (TM+KB)   // 2052

// ---------------- kernel 1: row means of r_emer + u-partials (u = W^T w_gate)
// blocks 0..4095  : one wave per row, mean over 2048 floats (134 MB read)
// blocks 4096..4159: 64 blocks computing partials[di][f] = sum_{d in chunk di} w_gate[d]*W[d][f]
__global__ __launch_bounds__(256) void k_mean_u(
    const float* __restrict__ r_emer, const float* __restrict__ W,
    const float* __restrict__ w_gate,
    float* __restrict__ micro_res, float* __restrict__ partials)
{
    const int tid = threadIdx.x;
    const int blk = blockIdx.x;
    if (blk < 4096) {
        const int lane = tid & 63, wave = tid >> 6;
        const int row = blk * 4 + wave;          // 0 .. 16383 (b*TU + t)
        const float4* rp = (const float4*)(r_emer + (size_t)row * FF);
        float s = 0.0f;
        #pragma unroll
        for (int j = 0; j < 8; ++j) {
            float4 v = rp[lane + 64 * j];
            s += v.x + v.y + v.z + v.w;
        }
        #pragma unroll
        for (int off = 32; off >= 1; off >>= 1)
            s += __shfl_down(s, off, 64);
        if (lane == 0) micro_res[row] = s * (1.0f / 2048.0f);
    } else {
        const int i  = blk - 4096;      // 0..63
        const int di = i >> 3;          // d-chunk 0..7 (128 d's each)
        const int f  = (i & 7) * 256 + tid;   // 0..2047
        const int d0 = di * 128;
        const float* wp = W + (size_t)d0 * FF + f;
        float acc = 0.0f;
        #pragma unroll 4
        for (int d = 0; d < 128; ++d)
            acc += w_gate[d0 + d] * wp[(size_t)d * FF];
        partials[di * FF + f] = acc;
    }
}

// ---------------- kernel 2: per-batch top-4 + gate via u (no child needed) ---
__global__ __launch_bounds__(256) void k_topk_gate(
    const float* __restrict__ micro_res, const float* __restrict__ thr_bias,
    const float* __restrict__ o_micro, const float* __restrict__ partials,
    const float* __restrict__ b_gate,
    int* __restrict__ sel_out, float* __restrict__ s_out,
    float* __restrict__ cnt_out)
{
    __shared__ float res[TU];     // 16 KB
    __shared__ float rv[256];
    __shared__ int   ri[256];
    __shared__ int   sel[KB];
    __shared__ float selv[KB];
    __shared__ float red[4];

    const int b = blockIdx.x, tid = threadIdx.x;
    const int lane = tid & 63, wave = tid >> 6;
    const float* mr = micro_res + b * TU;
    for (int i = tid; i < TU; i += 256) res[i] = mr[i];
    __syncthreads();

    const float thr = 0.45f + tanhf(thr_bias[0]) * 0.2f;

    for (int p = 0; p < KB; ++p) {
        float bv = -1.0f; int bi = 0x7fffffff;
        for (int t = tid; t < TU - 1; t += 256) {
            bool skip = false;
            for (int q = 0; q < p; ++q) if (sel[q] == t) skip = true;
            if (skip) continue;
            float pr = (res[t] + res[t + 1]) * 0.5f;
            float sc = pr > thr ? pr : 0.0f;
            if (sc > bv || (sc == bv && t < bi)) { bv = sc; bi = t; }
        }
        rv[tid] = bv; ri[tid] = bi;
        __syncthreads();
        for (int s = 128; s >= 1; s >>= 1) {
            if (tid < s) {
                float ov = rv[tid + s]; int oi = ri[tid + s];
                if (ov > rv[tid] || (ov == rv[tid] && oi < ri[tid])) {
                    rv[tid] = ov; ri[tid] = oi;
                }
            }
            __syncthreads();
        }
        if (tid == 0) { sel[p] = ri[0]; selv[p] = rv[0]; }
        __syncthreads();
    }

    // u-slice for this thread's 8 features: f = tid*8 .. tid*8+7
    float su[8];
    #pragma unroll
    for (int j = 0; j < 8; ++j) su[j] = 0.0f;
    const float4* pp = (const float4*)partials;   // [8][2048] as float4[8][512]
    #pragma unroll
    for (int di = 0; di < 8; ++di) {
        float4 p0 = pp[di * 512 + tid * 2];
        float4 p1 = pp[di * 512 + tid * 2 + 1];
        su[0] += p0.x; su[1] += p0.y; su[2] += p0.z; su[3] += p0.w;
        su[4] += p1.x; su[5] += p1.y; su[6] += p1.z; su[7] += p1.w;
    }

    // gate_k = sigmoid(u . comb_k + b);  comb_k = [o_micro[idx], o_micro[idx+1]]
    for (int k = 0; k < KB; ++k) {
        const int idx = sel[k];
        const float* rowp = (tid < 128)
            ? o_micro + ((size_t)b * TU + idx) * DM + tid * 8
            : o_micro + ((size_t)b * TU + idx + 1) * DM + (tid - 128) * 8;
        float4 c0 = ((const float4*)rowp)[0];
        float4 c1 = ((const float4*)rowp)[1];
        float dp = c0.x*su[0] + c0.y*su[1] + c0.z*su[2] + c0.w*su[3]
                 + c1.x*su[4] + c1.y*su[5] + c1.z*su[6] + c1.w*su[7];
        #pragma unroll
        for (int off = 32; off >= 1; off >>= 1)
            dp += __shfl_down(dp, off, 64);
        if (lane == 0) red[wave] = dp;
        __syncthreads();
        if (tid == 0) {
            float dot  = red[0] + red[1] + red[2] + red[3] + b_gate[0];
            float gate = 1.0f / (1.0f + expf(-dot));
            float mask = selv[k] > 0.0f ? 1.0f : 0.0f;
            s_out[b * KB + k]   = gate * mask;
            sel_out[b * KB + k] = sel[k];
        }
        __syncthreads();   // protect red[] reuse
    }
    if (tid == 0) {
        int c = 0;
        #pragma unroll
        for (int k = 0; k < KB; ++k) c += (selv[k] > 0.0f) ? 1 : 0;
        cnt_out[b] = (float)c;
    }
}

// ---------------- kernel 3: child GEMV (pre-scaled) + o_macro copy + n_births
// blocks 0..1023   : d-blocks — out_child[r][d] = scale[r] * (comb[r] . W[d])
// blocks 1024..2047: copy o_macro -> out (batch-strided); block 1024 writes n_births
__global__ __launch_bounds__(256) void k_child_copy(
    const float* __restrict__ o_micro, const float* __restrict__ W,
    const float* __restrict__ o_macro,
    const int* __restrict__ sel_in, const float* __restrict__ s_in,
    const float* __restrict__ cnt_in, float* __restrict__ out)
{
    const int tid = threadIdx.x;
    if (blockIdx.x < DM) {
        const int d    = blockIdx.x;
        const int lane = tid & 63, wave = tid >> 6;
        const int f0   = tid * 8;

        __shared__ int   sidx[NROWS];
        __shared__ float ssc[NROWS];
        if (tid < NROWS) { sidx[tid] = sel_in[tid]; ssc[tid] = s_in[tid]; }
        __syncthreads();

        const float4* wp = (const float4*)(W + (size_t)d * FF + f0);
        const float4 w0 = wp[0], w1 = wp[1];

        float acc[NROWS];
        #pragma unroll
        for (int r = 0; r < NROWS; ++r) {
            const int bb  = r >> 2;
            const int idx = sidx[r];
            const float* srcrow;
            int fo;
            if (f0 < DM) { srcrow = o_micro + ((size_t)bb * TU + idx) * DM;     fo = f0; }
            else         { srcrow = o_micro + ((size_t)bb * TU + idx + 1) * DM; fo = f0 - DM; }
            const float4* cp = (const float4*)(srcrow + fo);
            float4 c0 = cp[0], c1 = cp[1];
            acc[r] = c0.x * w0.x + c0.y * w0.y + c0.z * w0.z + c0.w * w0.w
                   + c1.x * w1.x + c1.y * w1.y + c1.z * w1.z + c1.w * w1.w;
        }
        #pragma unroll
        for (int r = 0; r < NROWS; ++r) {
            float v = acc[r];
            #pragma unroll
            for (int off = 32; off >= 1; off >>= 1)
                v += __shfl_down(v, off, 64);
            acc[r] = v;
        }
        __shared__ float part[4][NROWS];
        if (lane == 0) {
            #pragma unroll
            for (int r = 0; r < NROWS; ++r) part[wave][r] = acc[r];
        }
        __syncthreads();
        if (tid < NROWS) {
            const int bb = tid >> 2, kk = tid & 3;
            float v = part[0][tid] + part[1][tid] + part[2][tid] + part[3][tid];
            out[((size_t)bb * OUT_TM + TM + kk) * DM + d] = v * ssc[tid];
        }
    } else {
        const int NF4       = BATCH * TM * DM / 4;   // 2097152
        const int PER_BATCH = TM * DM / 4;           // 524288 (2^19)
        const int DST_BATCH = OUT_TM * DM / 4;       // 525312
        const float4* src = (const float4*)o_macro;
        float4* dst = (float4*)out;
        const int cb = blockIdx.x - DM;              // 0..1023
        for (int e = cb * 256 + tid; e < NF4; e += 1024 * 256) {
            int b = e >> 19;
            int q = e & (PER_BATCH - 1);
            dst[b * DST_BATCH + q] = src[e];
        }
        if (blockIdx.x == DM && tid == 0)
            out[(size_t)BATCH * OUT_TM * DM] =
                cnt_in[0] + cnt_in[1] + cnt_in[2] + cnt_in[3];   // n_births
    }
}

extern "C" void kernel_launch(void* const* d_in, const int* in_sizes, int n_in,
                              void* d_out, int out_size, void* d_ws, size_t ws_size,
                              hipStream_t stream) {
    const float* o_micro   = (const float*)d_in[0];
    const float* o_macro   = (const float*)d_in[1];
    const float* r_emer    = (const float*)d_in[2];
    // d_in[3] chunk_size — unused by the reference
    const float* W_vesica  = (const float*)d_in[4];
    const float* w_gate    = (const float*)d_in[5];
    const float* b_gate    = (const float*)d_in[6];
    const float* thr_bias  = (const float*)d_in[7];
    float* out = (float*)d_out;

    // workspace layout (floats)
    float* wsf       = (float*)d_ws;
    float* micro_res = wsf;                    // 16384 floats
    float* partials  = wsf + 16384;            // 8*2048 floats
    int*   selArr    = (int*)(wsf + 32768);    // 16 ints
    float* sArr      = wsf + 32784;            // 16 floats (gate*mask)
    float* cntArr    = wsf + 32800;            // 4 floats

    k_mean_u   <<<4160, 256, 0, stream>>>(r_emer, W_vesica, w_gate, micro_res, partials);
    k_topk_gate<<<BATCH, 256, 0, stream>>>(micro_res, thr_bias, o_micro, partials,
                                           b_gate, selArr, sArr, cntArr);
    k_child_copy<<<2048, 256, 0, stream>>>(o_micro, W_vesica, o_macro,
                                           selArr, sArr, cntArr, out);
}